// Round 4
// baseline (204.988 us; speedup 1.0000x reference)
//
#include <hip/hip_runtime.h>

// Problem geometry: B=64, A=9, H=W=128, C=1000
// N4 = 64*9*4096 = 2,359,296 float4 units over (B,A,H,W).
// Grid: 4608 blocks x 256 threads x 2 units/thread = exact cover.
// Block b owns units [b*512, b*512+512): 8 chunks per 4096-unit plane,
// so ba = b>>3 and chunk = b&7 are scalar; all 10 tensor-plane base
// pointers are wave-uniform (SGPR pairs for the saddr load form).
static constexpr int HW4 = 4096;
static constexpr float LOGCLAMP = -100.0f;

typedef float v4f __attribute__((ext_vector_type(4)));

// ws layout: ws[0]=no_obj_confi, ws[1]=obj_confi, ws[2]=obj_coor, ws[3]=img_class

// Inline-asm load: dwordx4 from SGPR base + 32-bit VGPR offset.
// volatile => cannot be deleted, sunk, or reordered vs other volatile asm.
// The compiler's waitcnt pass does not track asm defs, so WE own the waits.
__device__ __forceinline__ v4f gld(unsigned voff, const void* base) {
    v4f d;
    asm volatile("global_load_dwordx4 %0, %1, %2"
                 : "=v"(d)
                 : "v"(voff), "s"(base));
    return d;
}

__device__ __forceinline__ void accum_unit(
    const v4f o, const v4f m,
    const v4f l0, const v4f l1, const v4f l2, const v4f l3,
    const v4f g0, const v4f g1, const v4f g2, const v4f g3,
    float& s_noobj, float& s_obj, float& s_coor)
{
    #pragma unroll
    for (int c = 0; c < 4; ++c) {
        const float d0 = l0[c] - g0[c];
        const float d1 = l1[c] - g1[c];
        const float d2 = l2[c] - g2[c];
        const float d3 = l3[c] - g3[c];
        const float sq = d0 * d0 + d1 * d1 + d2 * d2 + d3 * d3;
        const float lp  = fmaxf(__logf(o[c]),        LOGCLAMP);
        const float l1m = fmaxf(__logf(1.0f - o[c]), LOGCLAMP);
        s_noobj -= (1.0f - m[c]) * l1m;
        s_obj   -= m[c] * lp;
        s_coor  += m[c] * sq;
    }
}

__global__ __launch_bounds__(256) void main_loss_kernel(
    const float4* __restrict__ objects,   // (BA, HW4)
    const float4* __restrict__ locs,      // (BA, 4, HW4)
    const float4* __restrict__ gt,        // (BA, 5, HW4)
    float* __restrict__ ws)
{
    const int b   = blockIdx.x;
    const int tid = threadIdx.x;

    // Wave-uniform byte base pointers (land in SGPRs via the "s" constraint).
    const float4* pO  = objects + b * 512;
    const float4* gtb = gt   + (b >> 3) * 5 * HW4 + (b & 7) * 512;
    const float4* lcb = locs + (b >> 3) * 4 * HW4 + (b & 7) * 512;
    const void* pM  = (const void*)(gtb);
    const void* pG1 = (const void*)(gtb + 1 * HW4);
    const void* pG2 = (const void*)(gtb + 2 * HW4);
    const void* pG3 = (const void*)(gtb + 3 * HW4);
    const void* pG4 = (const void*)(gtb + 4 * HW4);
    const void* pL0 = (const void*)(lcb);
    const void* pL1 = (const void*)(lcb + 1 * HW4);
    const void* pL2 = (const void*)(lcb + 2 * HW4);
    const void* pL3 = (const void*)(lcb + 3 * HW4);

    const unsigned voff0 = (unsigned)tid * 16u;          // unit 0: r = tid
    const unsigned voff1 = voff0 + 4096u;                // unit 1: r = tid+256

    // ---- issue ALL 20 loads before any wait ----
    v4f oA  = gld(voff0, (const void*)pO);
    v4f mA  = gld(voff0, pM);
    v4f lA0 = gld(voff0, pL0);
    v4f lA1 = gld(voff0, pL1);
    v4f lA2 = gld(voff0, pL2);
    v4f lA3 = gld(voff0, pL3);
    v4f gA1 = gld(voff0, pG1);
    v4f gA2 = gld(voff0, pG2);
    v4f gA3 = gld(voff0, pG3);
    v4f gA4 = gld(voff0, pG4);

    v4f oB  = gld(voff1, (const void*)pO);
    v4f mB  = gld(voff1, pM);
    v4f lB0 = gld(voff1, pL0);
    v4f lB1 = gld(voff1, pL1);
    v4f lB2 = gld(voff1, pL2);
    v4f lB3 = gld(voff1, pL3);
    v4f gB1 = gld(voff1, pG1);
    v4f gB2 = gld(voff1, pG2);
    v4f gB3 = gld(voff1, pG3);
    v4f gB4 = gld(voff1, pG4);

    float s_noobj = 0.0f, s_obj = 0.0f, s_coor = 0.0f;

    // Batch A ready when <=10 loads outstanding (B still in flight).
    asm volatile("s_waitcnt vmcnt(10)" ::: "memory");
    __builtin_amdgcn_sched_barrier(0);
    accum_unit(oA, mA, lA0, lA1, lA2, lA3, gA1, gA2, gA3, gA4,
               s_noobj, s_obj, s_coor);

    asm volatile("s_waitcnt vmcnt(0)" ::: "memory");
    __builtin_amdgcn_sched_barrier(0);
    accum_unit(oB, mB, lB0, lB1, lB2, lB3, gB1, gB2, gB3, gB4,
               s_noobj, s_obj, s_coor);

    // wave64 reduce all three sums
    #pragma unroll
    for (int off = 32; off > 0; off >>= 1) {
        s_noobj += __shfl_down(s_noobj, off, 64);
        s_obj   += __shfl_down(s_obj,   off, 64);
        s_coor  += __shfl_down(s_coor,  off, 64);
    }

    __shared__ float red[3][4];
    const int lane = threadIdx.x & 63;
    const int wid  = threadIdx.x >> 6;
    if (lane == 0) {
        red[0][wid] = s_noobj;
        red[1][wid] = s_obj;
        red[2][wid] = s_coor;
    }
    __syncthreads();
    if (threadIdx.x == 0) {
        atomicAdd(&ws[0], red[0][0] + red[0][1] + red[0][2] + red[0][3]);
        atomicAdd(&ws[1], red[1][0] + red[1][1] + red[1][2] + red[1][3]);
        atomicAdd(&ws[2], red[2][0] + red[2][1] + red[2][2] + red[2][3]);
    }
}

// img_class_loss: one block per batch row, C=1000
__global__ __launch_bounds__(256) void class_loss_kernel(
    const float* __restrict__ scores,   // (64, 1000)
    const int*   __restrict__ label,    // (64,)
    float* __restrict__ ws)
{
    const int b = blockIdx.x;
    const float* row = scores + b * 1000;

    float mx = -INFINITY;
    for (int i = threadIdx.x; i < 1000; i += 256) mx = fmaxf(mx, row[i]);
    #pragma unroll
    for (int off = 32; off > 0; off >>= 1) mx = fmaxf(mx, __shfl_down(mx, off, 64));

    __shared__ float smax[4];
    const int lane = threadIdx.x & 63;
    const int wid  = threadIdx.x >> 6;
    if (lane == 0) smax[wid] = mx;
    __syncthreads();
    mx = fmaxf(fmaxf(smax[0], smax[1]), fmaxf(smax[2], smax[3]));

    float se = 0.0f;
    for (int i = threadIdx.x; i < 1000; i += 256) se += __expf(row[i] - mx);
    #pragma unroll
    for (int off = 32; off > 0; off >>= 1) se += __shfl_down(se, off, 64);

    __shared__ float ssum[4];
    if (lane == 0) ssum[wid] = se;
    __syncthreads();
    if (threadIdx.x == 0) {
        se = ssum[0] + ssum[1] + ssum[2] + ssum[3];
        const float logp = row[label[b]] - mx - __logf(se);
        atomicAdd(&ws[3], -logp * (1.0f / 64.0f));   // mean over B
    }
}

__global__ void finalize_kernel(const float* __restrict__ ws, float* __restrict__ out)
{
    // IMG_CLASS_WEIGHT*class + (0.5*noobj + 1.0*obj + 5.0*coor)/B
    out[0] = ws[3] + (0.5f * ws[0] + 1.0f * ws[1] + 5.0f * ws[2]) * (1.0f / 64.0f);
}

extern "C" void kernel_launch(void* const* d_in, const int* in_sizes, int n_in,
                              void* d_out, int out_size, void* d_ws, size_t ws_size,
                              hipStream_t stream)
{
    const float* objects = (const float*)d_in[0];   // (64,9,128,128)
    const float* scores  = (const float*)d_in[1];   // (64,1000)
    const float* locs    = (const float*)d_in[2];   // (64,9,4,128,128)
    const int*   label   = (const int*)d_in[3];     // (64,)
    const float* gt      = (const float*)d_in[4];   // (64,9,5,128,128)
    float* ws  = (float*)d_ws;
    float* out = (float*)d_out;

    hipMemsetAsync(ws, 0, 4 * sizeof(float), stream);

    main_loss_kernel<<<4608, 256, 0, stream>>>(
        (const float4*)objects, (const float4*)locs, (const float4*)gt, ws);
    class_loss_kernel<<<64, 256, 0, stream>>>(scores, label, ws);
    finalize_kernel<<<1, 1, 0, stream>>>(ws, out);
}

// Round 6
// 127.412 us; speedup vs baseline: 1.6089x; 1.6089x over previous
//
#include <hip/hip_runtime.h>

// Problem geometry: B=64, A=9, H=W=128, C=1000
// N4 = 64*9*4096 = 2,359,296 float4 units over (B,A,H,W).
// chunk = 256 float4 (4 KB per tensor plane). 16 chunks per plane.
// Grid: 2304 blocks x 4 chunks/block = 9216 chunks = exact cover.
// Block b handles chunks 4b..4b+3 -> all within plane ba = b>>2
// (4b mod 16 in {0,4,8,12}), so every base is wave-uniform.
static constexpr int HW4 = 4096;
static constexpr float LOGCLAMP = -100.0f;

// ws layout: ws[0]=no_obj_confi, ws[1]=obj_confi, ws[2]=obj_coor, ws[3]=img_class

// Async HBM->LDS, 16 B per lane. LDS dest = wave-uniform base + lane*16;
// global src is per-lane. Data never touches VGPRs => the register
// allocator cannot serialize the batch. Counted by vmcnt.
__device__ __forceinline__ void stage16(const float4* g, float4* l) {
    __builtin_amdgcn_global_load_lds(
        (const __attribute__((address_space(1))) void*)g,
        (__attribute__((address_space(3))) void*)l,
        16, 0, 0);
}

__global__ __launch_bounds__(256) void main_loss_kernel(
    const float4* __restrict__ objects,   // (BA, HW4)
    const float4* __restrict__ locs,      // (BA, 4, HW4)
    const float4* __restrict__ gt,        // (BA, 5, HW4)
    float* __restrict__ ws)
{
    // LDS: 10 planes x 256 float4 = 40 KB  (plane 0 = o, 1 = m,
    // 2..5 = gt coords, 6..9 = locs coords)
    __shared__ float4 lds[10 * 256];

    const int b    = blockIdx.x;
    const int tid  = threadIdx.x;
    const int wb   = tid & ~63;           // wave base (wave-uniform)

    const int ba = b >> 2;                // plane index, fixed for the block
    const float4* gtb = gt   + ba * 5 * HW4;
    const float4* lcb = locs + ba * 4 * HW4;

    float s_noobj = 0.0f, s_obj = 0.0f, s_coor = 0.0f;

    #pragma unroll 1
    for (int r = 0; r < 4; ++r) {
        const int chunk = b * 4 + r;          // global chunk id
        const int c4    = chunk & 15;         // chunk within plane
        const int off   = c4 * 256;           // float4 offset within plane

        // ---- stage all 10 planes (40 KB in flight, zero VGPR cost) ----
        stage16(objects + chunk * 256 + tid, lds + 0 * 256 + wb);
        stage16(gtb + 0 * HW4 + off + tid,   lds + 1 * 256 + wb);
        stage16(gtb + 1 * HW4 + off + tid,   lds + 2 * 256 + wb);
        stage16(gtb + 2 * HW4 + off + tid,   lds + 3 * 256 + wb);
        stage16(gtb + 3 * HW4 + off + tid,   lds + 4 * 256 + wb);
        stage16(gtb + 4 * HW4 + off + tid,   lds + 5 * 256 + wb);
        stage16(lcb + 0 * HW4 + off + tid,   lds + 6 * 256 + wb);
        stage16(lcb + 1 * HW4 + off + tid,   lds + 7 * 256 + wb);
        stage16(lcb + 2 * HW4 + off + tid,   lds + 8 * 256 + wb);
        stage16(lcb + 3 * HW4 + off + tid,   lds + 9 * 256 + wb);

        asm volatile("s_waitcnt vmcnt(0)" ::: "memory");
        __syncthreads();

        // ---- compute from LDS (contiguous ds_read_b128, conflict-free) ----
        const float4 o  = lds[0 * 256 + tid];
        const float4 m  = lds[1 * 256 + tid];
        const float4 g0 = lds[2 * 256 + tid];
        const float4 g1 = lds[3 * 256 + tid];
        const float4 g2 = lds[4 * 256 + tid];
        const float4 g3 = lds[5 * 256 + tid];
        const float4 l0 = lds[6 * 256 + tid];
        const float4 l1 = lds[7 * 256 + tid];
        const float4 l2 = lds[8 * 256 + tid];
        const float4 l3 = lds[9 * 256 + tid];

        {
            const float d0 = l0.x - g0.x, d1 = l1.x - g1.x,
                        d2 = l2.x - g2.x, d3 = l3.x - g3.x;
            const float sq = d0 * d0 + d1 * d1 + d2 * d2 + d3 * d3;
            const float lp  = fmaxf(__logf(o.x),        LOGCLAMP);
            const float l1m = fmaxf(__logf(1.0f - o.x), LOGCLAMP);
            s_noobj -= (1.0f - m.x) * l1m;
            s_obj   -= m.x * lp;
            s_coor  += m.x * sq;
        }
        {
            const float d0 = l0.y - g0.y, d1 = l1.y - g1.y,
                        d2 = l2.y - g2.y, d3 = l3.y - g3.y;
            const float sq = d0 * d0 + d1 * d1 + d2 * d2 + d3 * d3;
            const float lp  = fmaxf(__logf(o.y),        LOGCLAMP);
            const float l1m = fmaxf(__logf(1.0f - o.y), LOGCLAMP);
            s_noobj -= (1.0f - m.y) * l1m;
            s_obj   -= m.y * lp;
            s_coor  += m.y * sq;
        }
        {
            const float d0 = l0.z - g0.z, d1 = l1.z - g1.z,
                        d2 = l2.z - g2.z, d3 = l3.z - g3.z;
            const float sq = d0 * d0 + d1 * d1 + d2 * d2 + d3 * d3;
            const float lp  = fmaxf(__logf(o.z),        LOGCLAMP);
            const float l1m = fmaxf(__logf(1.0f - o.z), LOGCLAMP);
            s_noobj -= (1.0f - m.z) * l1m;
            s_obj   -= m.z * lp;
            s_coor  += m.z * sq;
        }
        {
            const float d0 = l0.w - g0.w, d1 = l1.w - g1.w,
                        d2 = l2.w - g2.w, d3 = l3.w - g3.w;
            const float sq = d0 * d0 + d1 * d1 + d2 * d2 + d3 * d3;
            const float lp  = fmaxf(__logf(o.w),        LOGCLAMP);
            const float l1m = fmaxf(__logf(1.0f - o.w), LOGCLAMP);
            s_noobj -= (1.0f - m.w) * l1m;
            s_obj   -= m.w * lp;
            s_coor  += m.w * sq;
        }

        __syncthreads();   // protect LDS before next round's staging
    }

    // wave64 reduce all three sums
    #pragma unroll
    for (int off = 32; off > 0; off >>= 1) {
        s_noobj += __shfl_down(s_noobj, off, 64);
        s_obj   += __shfl_down(s_obj,   off, 64);
        s_coor  += __shfl_down(s_coor,  off, 64);
    }

    __shared__ float red[3][4];
    const int lane = threadIdx.x & 63;
    const int wid  = threadIdx.x >> 6;
    if (lane == 0) {
        red[0][wid] = s_noobj;
        red[1][wid] = s_obj;
        red[2][wid] = s_coor;
    }
    __syncthreads();
    if (threadIdx.x == 0) {
        atomicAdd(&ws[0], red[0][0] + red[0][1] + red[0][2] + red[0][3]);
        atomicAdd(&ws[1], red[1][0] + red[1][1] + red[1][2] + red[1][3]);
        atomicAdd(&ws[2], red[2][0] + red[2][1] + red[2][2] + red[2][3]);
    }
}

// img_class_loss: one block per batch row, C=1000
__global__ __launch_bounds__(256) void class_loss_kernel(
    const float* __restrict__ scores,   // (64, 1000)
    const int*   __restrict__ label,    // (64,)
    float* __restrict__ ws)
{
    const int b = blockIdx.x;
    const float* row = scores + b * 1000;

    float mx = -INFINITY;
    for (int i = threadIdx.x; i < 1000; i += 256) mx = fmaxf(mx, row[i]);
    #pragma unroll
    for (int off = 32; off > 0; off >>= 1) mx = fmaxf(mx, __shfl_down(mx, off, 64));

    __shared__ float smax[4];
    const int lane = threadIdx.x & 63;
    const int wid  = threadIdx.x >> 6;
    if (lane == 0) smax[wid] = mx;
    __syncthreads();
    mx = fmaxf(fmaxf(smax[0], smax[1]), fmaxf(smax[2], smax[3]));

    float se = 0.0f;
    for (int i = threadIdx.x; i < 1000; i += 256) se += __expf(row[i] - mx);
    #pragma unroll
    for (int off = 32; off > 0; off >>= 1) se += __shfl_down(se, off, 64);

    __shared__ float ssum[4];
    if (lane == 0) ssum[wid] = se;
    __syncthreads();
    if (threadIdx.x == 0) {
        se = ssum[0] + ssum[1] + ssum[2] + ssum[3];
        const float logp = row[label[b]] - mx - __logf(se);
        atomicAdd(&ws[3], -logp * (1.0f / 64.0f));   // mean over B
    }
}

__global__ void finalize_kernel(const float* __restrict__ ws, float* __restrict__ out)
{
    // IMG_CLASS_WEIGHT*class + (0.5*noobj + 1.0*obj + 5.0*coor)/B
    out[0] = ws[3] + (0.5f * ws[0] + 1.0f * ws[1] + 5.0f * ws[2]) * (1.0f / 64.0f);
}

extern "C" void kernel_launch(void* const* d_in, const int* in_sizes, int n_in,
                              void* d_out, int out_size, void* d_ws, size_t ws_size,
                              hipStream_t stream)
{
    const float* objects = (const float*)d_in[0];   // (64,9,128,128)
    const float* scores  = (const float*)d_in[1];   // (64,1000)
    const float* locs    = (const float*)d_in[2];   // (64,9,4,128,128)
    const int*   label   = (const int*)d_in[3];     // (64,)
    const float* gt      = (const float*)d_in[4];   // (64,9,5,128,128)
    float* ws  = (float*)d_ws;
    float* out = (float*)d_out;

    hipMemsetAsync(ws, 0, 4 * sizeof(float), stream);

    main_loss_kernel<<<2304, 256, 0, stream>>>(
        (const float4*)objects, (const float4*)locs, (const float4*)gt, ws);
    class_loss_kernel<<<64, 256, 0, stream>>>(scores, label, ws);
    finalize_kernel<<<1, 1, 0, stream>>>(ws, out);
}